// Round 5
// baseline (336.887 us; speedup 1.0000x reference)
//
#include <hip/hip_runtime.h>
#include <hip/hip_bf16.h>

// GCN on MI355X. Pipeline:
//   CSR-by-dst via two-level bucket binning (no random 4B scatter to HBM)
//   gemm128<fp32 A>  : x @ W1 -> bufA (bf16)
//   aggregate_mid    : gather-sum + bias + relu -> bufB (bf16)
//   gemm128<bf16 A>  : bufB @ W2 -> bufA (bf16)
//   aggregate_out    : gather-sum + bias + relu fused with @Wc + bc -> out
// Aggregates: 4 quarter-waves gather 4 edges/instruction (16B/lane),
// unroll x4 (16 edges in flight), cross-quarter shfl_xor reduce.
// Classifier weights held in 32 registers/lane (R4's LDS layout was a
// 16-way bank conflict: sub*128 % 32 == 0). h bf16; accum fp32. n <= 65536.

typedef unsigned int uint;

#define NPB 256                 // nodes per bucket
#define MAXBKT 256              // max buckets (n <= 65536)

static __device__ __forceinline__ unsigned short f2bf(float f) {
    unsigned u = __float_as_uint(f);
    u += 0x7fffu + ((u >> 16) & 1u);   // round-to-nearest-even
    return (unsigned short)(u >> 16);
}
static __device__ __forceinline__ uint pack2(float a, float b) {
    return (uint)f2bf(a) | ((uint)f2bf(b) << 16);
}
static __device__ __forceinline__ float lo2f(uint u) { return __uint_as_float(u << 16); }
static __device__ __forceinline__ float hi2f(uint u) { return __uint_as_float(u & 0xffff0000u); }

#define UNPACK8(dst, u)                                        \
    dst[0] = lo2f(u.x); dst[1] = hi2f(u.x);                    \
    dst[2] = lo2f(u.y); dst[3] = hi2f(u.y);                    \
    dst[4] = lo2f(u.z); dst[5] = hi2f(u.z);                    \
    dst[6] = lo2f(u.w); dst[7] = hi2f(u.w);

// ---------------- CSR build (bucketed) ----------------

__global__ __launch_bounds__(256) void bucket_hist(const int* __restrict__ dst,
                                                   int* __restrict__ bcount,
                                                   int E, int nbuckets) {
    __shared__ int h[MAXBKT];
    int tid = threadIdx.x;
    h[tid] = 0;
    __syncthreads();
    int chunk = (E + gridDim.x - 1) / gridDim.x;
    int i0 = blockIdx.x * chunk;
    int i1 = min(E, i0 + chunk);
    for (int i = i0 + tid; i < i1; i += 256) atomicAdd(&h[dst[i] >> 8], 1);
    __syncthreads();
    if (tid < nbuckets && h[tid]) atomicAdd(&bcount[tid], h[tid]);
}

__global__ __launch_bounds__(256) void scan196(const int* __restrict__ bcount,
                                               int* __restrict__ bbase,
                                               int* __restrict__ bcursor,
                                               int nbuckets, int E) {
    __shared__ int s[MAXBKT];
    int t = threadIdx.x;
    int v = (t < nbuckets) ? bcount[t] : 0;
    s[t] = v;
    __syncthreads();
    for (int d = 1; d < 256; d <<= 1) {
        int x = (t >= d) ? s[t - d] : 0;
        __syncthreads();
        s[t] += x;
        __syncthreads();
    }
    if (t < nbuckets) {
        int ex = s[t] - v;
        bbase[t] = ex;
        bcursor[t] = ex;
    }
    if (t == 0) bbase[nbuckets] = E;
}

__global__ __launch_bounds__(256) void bin_edges(const int* __restrict__ src,
                                                 const int* __restrict__ dst,
                                                 int* __restrict__ bcursor,
                                                 uint* __restrict__ pay,
                                                 int E, int nbuckets) {
    __shared__ int h[MAXBKT];
    __shared__ int base[MAXBKT];
    int tid = threadIdx.x;
    h[tid] = 0;
    __syncthreads();
    int chunk = (E + gridDim.x - 1) / gridDim.x;
    int i0 = blockIdx.x * chunk;
    int i1 = min(E, i0 + chunk);
    for (int i = i0 + tid; i < i1; i += 256) atomicAdd(&h[dst[i] >> 8], 1);
    __syncthreads();
    if (tid < nbuckets) base[tid] = h[tid] ? atomicAdd(&bcursor[tid], h[tid]) : 0;
    __syncthreads();
    h[tid] = 0;
    __syncthreads();
    for (int i = i0 + tid; i < i1; i += 256) {
        int d = dst[i];
        int b = d >> 8;
        int pos = base[b] + atomicAdd(&h[b], 1);
        pay[pos] = (uint)src[i] | ((uint)(d & 255) << 24);
    }
}

__global__ __launch_bounds__(256) void build_rows(const uint* __restrict__ pay,
                                                  const int* __restrict__ bbase,
                                                  int* __restrict__ rowstart,
                                                  float* __restrict__ dinv,
                                                  int* __restrict__ colidx,
                                                  int n, int E, int nbuckets) {
    __shared__ int hist[NPB];
    __shared__ int sc[NPB];
    __shared__ int cur[NPB];
    int tid = threadIdx.x;
    int b = blockIdx.x;
    int node0 = b * NPB;
    int s = bbase[b], e = bbase[b + 1];

    hist[tid] = 0;
    __syncthreads();
    for (int i = s + tid; i < e; i += 256) atomicAdd(&hist[pay[i] >> 24], 1);
    __syncthreads();

    int v = hist[tid];
    sc[tid] = v;
    __syncthreads();
    for (int d = 1; d < 256; d <<= 1) {
        int x = (tid >= d) ? sc[tid - d] : 0;
        __syncthreads();
        sc[tid] += x;
        __syncthreads();
    }
    int excl = sc[tid] - v;
    cur[tid] = s + excl;
    int node = node0 + tid;
    if (node < n) {
        rowstart[node] = s + excl;
        dinv[node] = rsqrtf((float)(v + 1));  // +1 self-loop
    }
    if (b == nbuckets - 1 && tid == 0) rowstart[n] = E;
    __syncthreads();

    for (int i = s + tid; i < e; i += 256) {
        uint p = pay[i];
        int pos = atomicAdd(&cur[p >> 24], 1);
        colidx[pos] = (int)(p & 0xffffffu);
    }
}

// ---------------- GEMM n x 128 @ 128 x 128, bf16 packed output ----------------
template <bool A_BF16>
__global__ __launch_bounds__(256) void gemm128(const void* __restrict__ Xv,
                                               const float* __restrict__ W,
                                               uint* __restrict__ Yb, int n) {
    __shared__ float sW[32 * 128];  // 16 KB
    const int tid = threadIdx.x;
    const int row0 = blockIdx.x * 64;
    const int ty = tid >> 4, tx = tid & 15;
    const int c0 = tx * 4;
    int r[4];
#pragma unroll
    for (int i = 0; i < 4; ++i) {
        int rr = row0 + ty * 4 + i;
        r[i] = rr < n ? rr : n - 1;
    }

    float acc[4][8];
#pragma unroll
    for (int i = 0; i < 4; ++i)
#pragma unroll
        for (int j = 0; j < 8; ++j) acc[i][j] = 0.f;

    for (int kc = 0; kc < 128; kc += 32) {
        __syncthreads();
        {
            const float4* W4 = (const float4*)(W + kc * 128);
            float4* s4 = (float4*)sW;
#pragma unroll
            for (int i = 0; i < 4; ++i) s4[tid + 256 * i] = W4[tid + 256 * i];
        }
        __syncthreads();

        for (int k4 = 0; k4 < 32; k4 += 4) {
            float a[4][4];
            if (A_BF16) {
                const uint2* X2 = (const uint2*)Xv;
#pragma unroll
                for (int i = 0; i < 4; ++i) {
                    uint2 u = X2[(size_t)r[i] * 32 + ((kc + k4) >> 2)];
                    a[i][0] = lo2f(u.x); a[i][1] = hi2f(u.x);
                    a[i][2] = lo2f(u.y); a[i][3] = hi2f(u.y);
                }
            } else {
                const float4* X4 = (const float4*)Xv;
#pragma unroll
                for (int i = 0; i < 4; ++i) {
                    float4 vv = X4[(size_t)r[i] * 32 + ((kc + k4) >> 2)];
                    a[i][0] = vv.x; a[i][1] = vv.y; a[i][2] = vv.z; a[i][3] = vv.w;
                }
            }
#pragma unroll
            for (int kk = 0; kk < 4; ++kk) {
                const int k = k4 + kk;
                float4 w0 = *(const float4*)&sW[k * 128 + c0];
                float4 w1 = *(const float4*)&sW[k * 128 + 64 + c0];
                float wv[8] = {w0.x, w0.y, w0.z, w0.w, w1.x, w1.y, w1.z, w1.w};
#pragma unroll
                for (int i = 0; i < 4; ++i) {
                    float av = a[i][kk];
#pragma unroll
                    for (int j = 0; j < 8; ++j) acc[i][j] = fmaf(av, wv[j], acc[i][j]);
                }
            }
        }
    }

#pragma unroll
    for (int i = 0; i < 4; ++i) {
        int rr = row0 + ty * 4 + i;
        if (rr < n) {
            uint2 o0 = {pack2(acc[i][0], acc[i][1]), pack2(acc[i][2], acc[i][3])};
            uint2 o1 = {pack2(acc[i][4], acc[i][5]), pack2(acc[i][6], acc[i][7])};
            *(uint2*)&Yb[(size_t)rr * 64 + (c0 >> 1)] = o0;
            *(uint2*)&Yb[(size_t)rr * 64 + 32 + (c0 >> 1)] = o1;
        }
    }
}

// ---------------- aggregate core: 4 edges / load instr, 16 in flight --------
// Wave = 4 quarters of 16 lanes. Quarter q gathers edges base+q, +4+q,
// +8+q, +12+q with uint4 (16B/lane x 16 lanes = 256B row).
// Result acc[8] = cols sub*8..sub*8+8, complete after shfl_xor(16|32).
static __device__ __forceinline__ void gather_acc(const uint4* __restrict__ Hb4,
                                                  const int* __restrict__ rowstart,
                                                  const int* __restrict__ colidx,
                                                  const float* __restrict__ dinv,
                                                  int wid, int q, int sub,
                                                  float di, float acc[8]) {
    uint4 su = Hb4[(size_t)wid * 16 + sub];
    float wS = (q == 0) ? di : 0.f;   // self-loop counted once
    float t[8];
    UNPACK8(t, su);
#pragma unroll
    for (int j = 0; j < 8; ++j) acc[j] = wS * t[j];

    int s = rowstart[wid], e = rowstart[wid + 1];
    for (int base = s; base < e; base += 16) {
        int p0 = base + q, p1 = base + 4 + q, p2 = base + 8 + q, p3 = base + 12 + q;
        int c0 = (p0 < e) ? colidx[p0] : wid;
        int c1 = (p1 < e) ? colidx[p1] : wid;
        int c2 = (p2 < e) ? colidx[p2] : wid;
        int c3 = (p3 < e) ? colidx[p3] : wid;
        float w0 = (p0 < e) ? dinv[c0] : 0.f;
        float w1 = (p1 < e) ? dinv[c1] : 0.f;
        float w2 = (p2 < e) ? dinv[c2] : 0.f;
        float w3 = (p3 < e) ? dinv[c3] : 0.f;
        uint4 u0 = Hb4[(size_t)c0 * 16 + sub];
        uint4 u1 = Hb4[(size_t)c1 * 16 + sub];
        uint4 u2 = Hb4[(size_t)c2 * 16 + sub];
        uint4 u3 = Hb4[(size_t)c3 * 16 + sub];
        float a0[8], a1[8], a2[8], a3[8];
        UNPACK8(a0, u0);
        UNPACK8(a1, u1);
        UNPACK8(a2, u2);
        UNPACK8(a3, u3);
#pragma unroll
        for (int j = 0; j < 8; ++j) acc[j] = fmaf(w0, a0[j], acc[j]);
#pragma unroll
        for (int j = 0; j < 8; ++j) acc[j] = fmaf(w1, a1[j], acc[j]);
#pragma unroll
        for (int j = 0; j < 8; ++j) acc[j] = fmaf(w2, a2[j], acc[j]);
#pragma unroll
        for (int j = 0; j < 8; ++j) acc[j] = fmaf(w3, a3[j], acc[j]);
    }
#pragma unroll
    for (int j = 0; j < 8; ++j) {
        acc[j] += __shfl_xor(acc[j], 16, 64);
        acc[j] += __shfl_xor(acc[j], 32, 64);
    }
}

// middle layer: + bias, relu, bf16 out
__global__ __launch_bounds__(256) void aggregate_mid(const uint* __restrict__ Hb,
                                                     const int* __restrict__ rowstart,
                                                     const int* __restrict__ colidx,
                                                     const float* __restrict__ dinv,
                                                     const float* __restrict__ bias,
                                                     uint* __restrict__ Ob, int n) {
    int wid = blockIdx.x * 4 + (threadIdx.x >> 6);
    int lane = threadIdx.x & 63;
    if (wid >= n) return;
    int q = lane >> 4, sub = lane & 15;
    float di = dinv[wid];
    float acc[8];
    gather_acc((const uint4*)Hb, rowstart, colidx, dinv, wid, q, sub, di, acc);

    if (q == 0) {
        float4 b0 = ((const float4*)bias)[sub * 2];
        float4 b1 = ((const float4*)bias)[sub * 2 + 1];
        float o0 = fmaxf(fmaf(acc[0], di, b0.x), 0.f);
        float o1 = fmaxf(fmaf(acc[1], di, b0.y), 0.f);
        float o2 = fmaxf(fmaf(acc[2], di, b0.z), 0.f);
        float o3 = fmaxf(fmaf(acc[3], di, b0.w), 0.f);
        float o4 = fmaxf(fmaf(acc[4], di, b1.x), 0.f);
        float o5 = fmaxf(fmaf(acc[5], di, b1.y), 0.f);
        float o6 = fmaxf(fmaf(acc[6], di, b1.z), 0.f);
        float o7 = fmaxf(fmaf(acc[7], di, b1.w), 0.f);
        uint4 o;
        o.x = pack2(o0, o1); o.y = pack2(o2, o3);
        o.z = pack2(o4, o5); o.w = pack2(o6, o7);
        ((uint4*)Ob)[(size_t)wid * 16 + sub] = o;
    }
}

// final layer fused with classifier: out = relu(agg + b2) @ Wc + bc.
// Wc held in registers: lane needs Wc[sub*8+jj][q*4+cc] only (8 float4 loads).
__global__ __launch_bounds__(256) void aggregate_out(const uint* __restrict__ Hb,
                                                     const int* __restrict__ rowstart,
                                                     const int* __restrict__ colidx,
                                                     const float* __restrict__ dinv,
                                                     const float* __restrict__ bias,
                                                     const float* __restrict__ Wc,
                                                     const float* __restrict__ bc,
                                                     float* __restrict__ out, int n) {
    int wid = blockIdx.x * 4 + (threadIdx.x >> 6);
    int lane = threadIdx.x & 63;
    if (wid >= n) return;
    int q = lane >> 4, sub = lane & 15;

    float4 wreg[8];  // wreg[jj] = Wc[(sub*8+jj)][q*4 .. q*4+4]
    {
        const float4* W4 = (const float4*)Wc;  // row k = 4 float4s
#pragma unroll
        for (int jj = 0; jj < 8; ++jj) wreg[jj] = W4[(sub * 8 + jj) * 4 + q];
    }

    float di = dinv[wid];
    float acc[8];
    gather_acc((const uint4*)Hb, rowstart, colidx, dinv, wid, q, sub, di, acc);

    // f = relu(acc*di + b2) for cols k = sub*8..sub*8+8 (all lanes complete)
    float4 b0 = ((const float4*)bias)[sub * 2];
    float4 b1 = ((const float4*)bias)[sub * 2 + 1];
    float f[8];
    f[0] = fmaxf(fmaf(acc[0], di, b0.x), 0.f);
    f[1] = fmaxf(fmaf(acc[1], di, b0.y), 0.f);
    f[2] = fmaxf(fmaf(acc[2], di, b0.z), 0.f);
    f[3] = fmaxf(fmaf(acc[3], di, b0.w), 0.f);
    f[4] = fmaxf(fmaf(acc[4], di, b1.x), 0.f);
    f[5] = fmaxf(fmaf(acc[5], di, b1.y), 0.f);
    f[6] = fmaxf(fmaf(acc[6], di, b1.z), 0.f);
    f[7] = fmaxf(fmaf(acc[7], di, b1.w), 0.f);

    // quarter q computes output cols q*4..q*4+4 from its 8 k's (registers only)
    float pr[4] = {0.f, 0.f, 0.f, 0.f};
#pragma unroll
    for (int jj = 0; jj < 8; ++jj) {
        pr[0] = fmaf(f[jj], wreg[jj].x, pr[0]);
        pr[1] = fmaf(f[jj], wreg[jj].y, pr[1]);
        pr[2] = fmaf(f[jj], wreg[jj].z, pr[2]);
        pr[3] = fmaf(f[jj], wreg[jj].w, pr[3]);
    }
#pragma unroll
    for (int m = 1; m < 16; m <<= 1) {
#pragma unroll
        for (int cc = 0; cc < 4; ++cc) pr[cc] += __shfl_xor(pr[cc], m, 64);
    }
    if (sub == 0) {
        float4 bcq = ((const float4*)bc)[q];
        float4 o = {pr[0] + bcq.x, pr[1] + bcq.y, pr[2] + bcq.z, pr[3] + bcq.w};
        *(float4*)&out[(size_t)wid * 16 + q * 4] = o;
    }
}

// ---------------- launch ----------------

extern "C" void kernel_launch(void* const* d_in, const int* in_sizes, int n_in,
                              void* d_out, int out_size, void* d_ws, size_t ws_size,
                              hipStream_t stream) {
    const float* x  = (const float*)d_in[0];
    const int*   ei = (const int*)d_in[1];
    const float* W1 = (const float*)d_in[2];
    const float* b1 = (const float*)d_in[3];
    const float* W2 = (const float*)d_in[4];
    const float* b2 = (const float*)d_in[5];
    const float* Wc = (const float*)d_in[6];
    const float* bc = (const float*)d_in[7];
    float* out = (float*)d_out;

    const int n = in_sizes[0] / 128;  // 50000
    const int E = in_sizes[1] / 2;    // 1,600,000
    const int* src = ei;
    const int* dst = ei + E;
    const int nbuckets = (n + NPB - 1) / NPB;  // 196

    char* p = (char*)d_ws;
    auto alloc = [&](size_t bytes) {
        char* q = p;
        p += (bytes + 255) & ~(size_t)255;
        return q;
    };
    int*   bcount   = (int*)alloc(MAXBKT * 4);
    int*   bbase    = (int*)alloc((MAXBKT + 1) * 4);
    int*   bcursor  = (int*)alloc(MAXBKT * 4);
    int*   rowstart = (int*)alloc(((size_t)n + 1) * 4);
    int*   colidx   = (int*)alloc((size_t)E * 4);
    uint*  pay      = (uint*)alloc((size_t)E * 4);
    float* dinv     = (float*)alloc((size_t)n * 4);
    uint*  bufA     = (uint*)alloc((size_t)n * 64 * 4);  // bf16 h
    uint*  bufB     = (uint*)alloc((size_t)n * 64 * 4);
    if ((size_t)(p - (char*)d_ws) > ws_size) return;

    hipMemsetAsync(bcount, 0, MAXBKT * 4, stream);

    bucket_hist<<<256, 256, 0, stream>>>(dst, bcount, E, nbuckets);
    scan196<<<1, 256, 0, stream>>>(bcount, bbase, bcursor, nbuckets, E);
    bin_edges<<<256, 256, 0, stream>>>(src, dst, bcursor, pay, E, nbuckets);
    build_rows<<<nbuckets, 256, 0, stream>>>(pay, bbase, rowstart, dinv, colidx, n, E, nbuckets);

    gemm128<false><<<(n + 63) / 64, 256, 0, stream>>>(x, W1, bufA, n);
    aggregate_mid<<<(n + 3) / 4, 256, 0, stream>>>(bufA, rowstart, colidx, dinv, b1, bufB, n);
    gemm128<true><<<(n + 63) / 64, 256, 0, stream>>>(bufB, W2, bufA, n);
    aggregate_out<<<(n + 3) / 4, 256, 0, stream>>>(bufA, rowstart, colidx, dinv, b2, Wc, bc, out, n);
}